// Round 1
// baseline (352.456 us; speedup 1.0000x reference)
//
#include <hip/hip_runtime.h>

// Problem constants
constexpr int Bn = 16, Cn = 3, Tn = 16, Hn = 224, Wn = 224;
constexpr int PLANE = Hn * Wn;                 // 50176 floats per (b,c,t) plane
constexpr int THREADS = 256;
constexpr int FLOATS_PER_BLOCK = THREADS * 4;  // 1024
constexpr int BLOCKS_PER_PLANE = PLANE / FLOATS_PER_BLOCK; // 49 (exact)

constexpr float COLOR_STRENGTH = 0.3f;
constexpr float NOISE_STRENGTH = 0.02f;
constexpr float DROPOUT_PROB   = 0.05f;
constexpr float HFLIP_PROB     = 0.5f;
constexpr int   MAX_JITTER     = 3;

__global__ __launch_bounds__(THREADS) void aug_kernel(
    const float* __restrict__ video,
    const int*   __restrict__ jitter,
    const float* __restrict__ b_rand,
    const float* __restrict__ c_rand,
    const float* __restrict__ noise,
    const float* __restrict__ flip_rand,
    const float* __restrict__ drop_rand,
    float*       __restrict__ out)
{
    // blockIdx.y encodes (b, c, t); all derived values are wave-uniform.
    const int bct = blockIdx.y;
    const int t = bct & (Tn - 1);          // Tn = 16
    const int c = (bct >> 4) % Cn;
    const int b = bct / (Tn * Cn);

    // ---- per-sample scalar params (scalar loads; uniform within block) ----
    const int j = jitter[b] - MAX_JITTER;                  // [-3, 3]
    const int t_src = (t - j + Tn) & (Tn - 1);             // (t - j) mod 16

    const float bf = 1.0f + (b_rand[b] - 0.5f) * (2.0f * COLOR_STRENGTH);
    float cf = 1.0f + (c_rand[b] - 0.5f) * (2.0f * COLOR_STRENGTH);
    cf = fminf(fmaxf(cf, 0.1f), 3.0f);

    const bool flip = flip_rand[b] < HFLIP_PROB;

    bool any_keep = false;
    #pragma unroll
    for (int tt = 0; tt < Tn; ++tt)
        any_keep = any_keep || (drop_rand[b * Tn + tt] > DROPOUT_PROB);
    bool keep = drop_rand[b * Tn + t] > DROPOUT_PROB;
    if (t == 0) keep = keep || !any_keep;   // guarantee >=1 kept frame
    const float keepf = keep ? 1.0f : 0.0f;

    // ---- plane bases ----
    const int inPlane  = ((b * Cn + c) * Tn + t_src) * PLANE;  // rolled source
    const int outPlane = ((b * Cn + c) * Tn + t) * PLANE;      // output / noise

    // ---- this thread's 4 contiguous floats within the plane ----
    const int o = (blockIdx.x * THREADS + threadIdx.x) * 4;
    const int h = o / Wn;
    const int w = o - h * Wn;

    float4 v, nz;
    if (!flip) {
        v  = *(const float4*)(video + inPlane  + o);
        nz = *(const float4*)(noise + outPlane + o);
    } else {
        // out[w..w+3] = in[W-1-w .. W-4-w]  -> load mirrored float4, reverse
        const int ws = Wn - 4 - w;
        const float4 vr = *(const float4*)(video + inPlane  + h * Wn + ws);
        const float4 nr = *(const float4*)(noise + outPlane + h * Wn + ws);
        v  = make_float4(vr.w, vr.z, vr.y, vr.x);
        nz = make_float4(nr.w, nr.z, nr.y, nr.x);
    }

    auto apply = [&](float x, float n) -> float {
        x = fminf(fmaxf(x * bf, 0.0f), 1.0f);                    // brightness
        x = fminf(fmaxf((x - 0.5f) * cf + 0.5f, 0.0f), 1.0f);    // contrast
        x = fminf(fmaxf(x + n * NOISE_STRENGTH, 0.0f), 1.0f);    // noise
        return x * keepf;                                        // frame dropout
    };

    float4 r;
    r.x = apply(v.x, nz.x);
    r.y = apply(v.y, nz.y);
    r.z = apply(v.z, nz.z);
    r.w = apply(v.w, nz.w);

    *(float4*)(out + outPlane + o) = r;
}

extern "C" void kernel_launch(void* const* d_in, const int* in_sizes, int n_in,
                              void* d_out, int out_size, void* d_ws, size_t ws_size,
                              hipStream_t stream) {
    const float* video     = (const float*)d_in[0];
    const int*   jitter    = (const int*)  d_in[1];
    const float* b_rand    = (const float*)d_in[2];
    const float* c_rand    = (const float*)d_in[3];
    const float* noise     = (const float*)d_in[4];
    const float* flip_rand = (const float*)d_in[5];
    const float* drop_rand = (const float*)d_in[6];
    float*       out       = (float*)d_out;

    dim3 grid(BLOCKS_PER_PLANE, Bn * Cn * Tn);  // 49 x 768
    aug_kernel<<<grid, dim3(THREADS), 0, stream>>>(
        video, jitter, b_rand, c_rand, noise, flip_rand, drop_rand, out);
}

// Round 2
// 339.899 us; speedup vs baseline: 1.0369x; 1.0369x over previous
//
#include <hip/hip_runtime.h>

// Problem constants
constexpr int Bn = 16, Cn = 3, Tn = 16, Hn = 224, Wn = 224;
constexpr int PLANE = Hn * Wn;                 // 50176 floats per (b,c,t) plane
constexpr int F4_PER_PLANE = PLANE / 4;        // 12544 float4s
constexpr int THREADS = 256;
constexpr int PER_THREAD = 7;                  // 7*256 = 1792 float4/block; 12544/1792 = 7 blocks/plane exact
constexpr int BLOCKS_PER_PLANE = F4_PER_PLANE / (THREADS * PER_THREAD); // 7
constexpr int W4 = Wn / 4;                     // 56 float4 per row

constexpr float COLOR_STRENGTH = 0.3f;
constexpr float NOISE_STRENGTH = 0.02f;
constexpr float DROPOUT_PROB   = 0.05f;
constexpr float HFLIP_PROB     = 0.5f;
constexpr int   MAX_JITTER     = 3;

typedef float v4f __attribute__((ext_vector_type(4)));

__global__ __launch_bounds__(THREADS) void aug_kernel(
    const float* __restrict__ video,
    const int*   __restrict__ jitter,
    const float* __restrict__ b_rand,
    const float* __restrict__ c_rand,
    const float* __restrict__ noise,
    const float* __restrict__ flip_rand,
    const float* __restrict__ drop_rand,
    float*       __restrict__ out)
{
    // blockIdx.y encodes (b, c, t); all derived values are wave-uniform.
    const int bct = blockIdx.y;
    const int t = bct & (Tn - 1);          // Tn = 16
    const int c = (bct >> 4) % Cn;
    const int b = bct / (Tn * Cn);

    // ---- per-sample scalar params (uniform within block) ----
    const int j = jitter[b] - MAX_JITTER;                  // [-3, 3]
    const int t_src = (t - j + Tn) & (Tn - 1);             // (t - j) mod 16

    const float bf = 1.0f + (b_rand[b] - 0.5f) * (2.0f * COLOR_STRENGTH);
    float cf = 1.0f + (c_rand[b] - 0.5f) * (2.0f * COLOR_STRENGTH);
    cf = fminf(fmaxf(cf, 0.1f), 3.0f);

    const bool flip = flip_rand[b] < HFLIP_PROB;

    bool any_keep = false;
    #pragma unroll
    for (int tt = 0; tt < Tn; ++tt)
        any_keep = any_keep || (drop_rand[b * Tn + tt] > DROPOUT_PROB);
    bool keep = drop_rand[b * Tn + t] > DROPOUT_PROB;
    if (t == 0) keep = keep || !any_keep;   // guarantee >=1 kept frame
    const float keepf = keep ? 1.0f : 0.0f;

    // ---- plane bases (in float4 units) ----
    const int inPlane4  = (((b * Cn + c) * Tn + t_src)) * F4_PER_PLANE;  // rolled source
    const int outPlane4 = (((b * Cn + c) * Tn + t))     * F4_PER_PLANE;  // output / noise

    const v4f* __restrict__ vid4 = (const v4f*)video;
    const v4f* __restrict__ noi4 = (const v4f*)noise;
    v4f*       __restrict__ out4 = (v4f*)out;

    // Each thread: PER_THREAD float4s, strided by THREADS for coalescing.
    const int base = blockIdx.x * (PER_THREAD * THREADS) + threadIdx.x;

    // ---- issue all loads up front (forward-streaming for both streams) ----
    v4f v[PER_THREAD], nz[PER_THREAD];
    #pragma unroll
    for (int k = 0; k < PER_THREAD; ++k) {
        const int p = base + k * THREADS;
        v[k]  = __builtin_nontemporal_load(vid4 + inPlane4  + p);
        nz[k] = __builtin_nontemporal_load(noi4 + outPlane4 + p);
    }

    auto apply = [&](float x, float n) -> float {
        x = fminf(fmaxf(x * bf, 0.0f), 1.0f);                    // brightness
        x = fminf(fmaxf((x - 0.5f) * cf + 0.5f, 0.0f), 1.0f);    // contrast
        x = fminf(fmaxf(x + n * NOISE_STRENGTH, 0.0f), 1.0f);    // noise
        return x * keepf;                                        // frame dropout
    };

    #pragma unroll
    for (int k = 0; k < PER_THREAD; ++k) {
        const int p = base + k * THREADS;
        v4f r;
        r.x = apply(v[k].x, nz[k].x);
        r.y = apply(v[k].y, nz[k].y);
        r.z = apply(v[k].z, nz[k].z);
        r.w = apply(v[k].w, nz[k].w);

        if (!flip) {
            __builtin_nontemporal_store(r, out4 + outPlane4 + p);
        } else {
            // out[row, 4*(55-col)+3-i] = r[i] : mirrored float4, reversed lanes
            const int row  = p / W4;
            const int col  = p - row * W4;
            const int pd   = row * W4 + (W4 - 1 - col);
            v4f rr = { r.w, r.z, r.y, r.x };
            __builtin_nontemporal_store(rr, out4 + outPlane4 + pd);
        }
    }
}

extern "C" void kernel_launch(void* const* d_in, const int* in_sizes, int n_in,
                              void* d_out, int out_size, void* d_ws, size_t ws_size,
                              hipStream_t stream) {
    const float* video     = (const float*)d_in[0];
    const int*   jitter    = (const int*)  d_in[1];
    const float* b_rand    = (const float*)d_in[2];
    const float* c_rand    = (const float*)d_in[3];
    const float* noise     = (const float*)d_in[4];
    const float* flip_rand = (const float*)d_in[5];
    const float* drop_rand = (const float*)d_in[6];
    float*       out       = (float*)d_out;

    dim3 grid(BLOCKS_PER_PLANE, Bn * Cn * Tn);  // 7 x 768
    aug_kernel<<<grid, dim3(THREADS), 0, stream>>>(
        video, jitter, b_rand, c_rand, noise, flip_rand, drop_rand, out);
}